// Round 6
// baseline (173.608 us; speedup 1.0000x reference)
//
#include <hip/hip_runtime.h>

#define HH 512
#define WW 512
#define NBATCH 16
#define NBINS 512   // 511 real shells + 1 overflow (never accumulated)

#define PI_F 3.14159265358979323846f

// Swizzle for the per-wave FFT exchange region (512 float2): keeps all three
// access phases at the conflict-free b64 baseline (verified R3/R4, absmax 0).
#define SW(r) ((r) ^ (((r) >> 4) & 0xF))

__device__ __forceinline__ float2 cadd(float2 a, float2 b){ return make_float2(a.x+b.x, a.y+b.y); }
__device__ __forceinline__ float2 csub(float2 a, float2 b){ return make_float2(a.x-b.x, a.y-b.y); }
__device__ __forceinline__ float2 cmul(float2 a, float2 b){
    return make_float2(a.x*b.x - a.y*b.y, a.x*b.y + a.y*b.x);
}

// f32x2 <-> packed f16x2 (v_cvt_pkrtz_f16_f32 one-instr pack)
typedef __fp16 h2v __attribute__((ext_vector_type(2)));
__device__ __forceinline__ unsigned pack2(float2 v) {
    union { h2v h; unsigned u; } c;
    c.h = __builtin_amdgcn_cvt_pkrtz(v.x, v.y);
    return c.u;
}
__device__ __forceinline__ float2 unpack2(unsigned u) {
    union { unsigned u; __fp16 h[2]; } c; c.u = u;
    return make_float2((float)c.h[0], (float)c.h[1]);
}

// 8-point DFT, y_r = sum_u a_u * w8^{ru} (forward, w8 = exp(-i pi/4)).
__device__ __forceinline__ void dft8(const float2* a, float2* y) {
    const float s2 = 0.70710678118654752440f;
    float2 t02a = cadd(a[0], a[4]), t02s = csub(a[0], a[4]);
    float2 t13a = cadd(a[2], a[6]), t13s = csub(a[2], a[6]);
    float2 E0 = cadd(t02a, t13a);
    float2 E2 = csub(t02a, t13a);
    float2 E1 = make_float2(t02s.x + t13s.y, t02s.y - t13s.x);
    float2 E3 = make_float2(t02s.x - t13s.y, t02s.y + t13s.x);
    float2 u02a = cadd(a[1], a[5]), u02s = csub(a[1], a[5]);
    float2 u13a = cadd(a[3], a[7]), u13s = csub(a[3], a[7]);
    float2 O0 = cadd(u02a, u13a);
    float2 O2 = csub(u02a, u13a);
    float2 O1 = make_float2(u02s.x + u13s.y, u02s.y - u13s.x);
    float2 O3 = make_float2(u02s.x - u13s.y, u02s.y + u13s.x);
    float2 wO1 = make_float2(s2 * (O1.x + O1.y), s2 * (O1.y - O1.x));
    float2 wO2 = make_float2(O2.y, -O2.x);
    float2 wO3 = make_float2(s2 * (O3.y - O3.x), -s2 * (O3.x + O3.y));
    y[0] = cadd(E0, O0);  y[4] = csub(E0, O0);
    y[1] = cadd(E1, wO1); y[5] = csub(E1, wO1);
    y[2] = cadd(E2, wO2); y[6] = csub(E2, wO2);
    y[3] = cadd(E3, wO3); y[7] = csub(E3, wO3);
}

__device__ __forceinline__ void twiddle8(float base, float2* w) {
    float s1, c1, s4, c4;
    __sincosf(base, &s1, &c1);
    __sincosf(4.0f * base, &s4, &c4);
    w[0] = make_float2(1.0f, 0.0f);
    w[1] = make_float2(c1, s1);
    w[2] = cmul(w[1], w[1]);
    w[3] = cmul(w[2], w[1]);
    w[4] = make_float2(c4, s4);
    w[5] = cmul(w[4], w[1]);
    w[6] = cmul(w[4], w[2]);
    w[7] = cmul(w[4], w[3]);
}

// Two interleaved radix-8 Stockham 512-pt FFTs per wave (shared twiddles).
// a0/a1 in, y0/y1 out (natural order: y[r] = X[lane + 64r]).
__device__ __forceinline__ void fft512_x2(float2* rb0, float2* rb1, int lane,
                                          float2* a0, float2* a1,
                                          float2* y0, float2* y1) {
    float2 w[8], y[8];
    // stage 0
    twiddle8(-PI_F * (float)lane * (1.0f / 256.0f), w);
    dft8(a0, y);
#pragma unroll
    for (int r = 0; r < 8; ++r) rb0[SW(8 * lane + r)] = cmul(y[r], w[r]);
    dft8(a1, y);
#pragma unroll
    for (int r = 0; r < 8; ++r) rb1[SW(8 * lane + r)] = cmul(y[r], w[r]);
    __builtin_amdgcn_wave_barrier();
    // stage 1
#pragma unroll
    for (int u = 0; u < 8; ++u) a0[u] = rb0[SW(lane + 64 * u)];
#pragma unroll
    for (int u = 0; u < 8; ++u) a1[u] = rb1[SW(lane + 64 * u)];
    twiddle8(-PI_F * (float)(lane >> 3) * (1.0f / 32.0f), w);
    const int qb = (lane & 7) + ((lane >> 3) << 6);
    dft8(a0, y);
#pragma unroll
    for (int r = 0; r < 8; ++r) rb0[SW(qb + 8 * r)] = cmul(y[r], w[r]);
    dft8(a1, y);
#pragma unroll
    for (int r = 0; r < 8; ++r) rb1[SW(qb + 8 * r)] = cmul(y[r], w[r]);
    __builtin_amdgcn_wave_barrier();
    // stage 2 (twiddle-free)
#pragma unroll
    for (int u = 0; u < 8; ++u) a0[u] = rb0[SW(lane + 64 * u)];
#pragma unroll
    for (int u = 0; u < 8; ++u) a1[u] = rb1[SW(lane + 64 * u)];
    dft8(a0, y0);
    dft8(a1, y1);
}

// ---------------------------------------------------------------------------
// Row pass: block = 512 thr = 8 waves, 16 rows of one batch. Wave g owns rows
// 2g, 2g+1 (ILP-2). Two field passes (f=0: t, f=1: z-t). After the FFTs the
// 16x512 tile is transposed in LDS (f16-packed, pad 516 -> conflict-free) and
// stored as fieldsT[field][col][row] with exact 64B column segments.
// grid = NBATCH*32.
// ---------------------------------------------------------------------------
__global__ __launch_bounds__(512, 4)
void row_fft_kernel(const float2* __restrict__ z, const float2* __restrict__ t,
                    unsigned* __restrict__ fieldsT) {
    __shared__ float2 buf[16 * 512];     // 64 KiB; f16 tile aliases low 33 KiB
    const int tid  = threadIdx.x;
    const int lane = tid & 63;
    const int g    = tid >> 6;
    const int bid  = blockIdx.x;
    const int hg   = bid & 31;
    const int b    = bid >> 5;
    const int hb   = hg << 4;
    const int r0   = hb | (g << 1);
    const size_t off0 = (((size_t)b * HH) + r0) << 9;   // float2 index of row r0
    const size_t off1 = off0 + 512;

    float2* rb0 = buf + ((g << 1) << 9);
    float2* rb1 = rb0 + 512;
    unsigned* tile = (unsigned*)buf;     // tile[rr][c]: idx = rr*516 + c

#pragma unroll
    for (int f = 0; f < 2; ++f) {
        float2 a0[8], a1[8];
        if (f == 0) {
#pragma unroll
            for (int u = 0; u < 8; ++u) a0[u] = t[off0 + lane + 64 * u];
#pragma unroll
            for (int u = 0; u < 8; ++u) a1[u] = t[off1 + lane + 64 * u];
        } else {
#pragma unroll
            for (int u = 0; u < 8; ++u) {
                float2 zv = z[off0 + lane + 64 * u];
                float2 tv = t[off0 + lane + 64 * u];
                a0[u] = make_float2(zv.x - tv.x, zv.y - tv.y);
            }
#pragma unroll
            for (int u = 0; u < 8; ++u) {
                float2 zv = z[off1 + lane + 64 * u];
                float2 tv = t[off1 + lane + 64 * u];
                a1[u] = make_float2(zv.x - tv.x, zv.y - tv.y);
            }
        }
        float2 y0[8], y1[8];
        fft512_x2(rb0, rb1, lane, a0, a1, y0, y1);

        __syncthreads();                 // FFT regions dead -> alias as tile
        const int rr0 = g << 1, rr1 = rr0 | 1;
#pragma unroll
        for (int r = 0; r < 8; ++r) {
            int c = lane + (r << 6);
            tile[rr0 * 516 + c] = pack2(y0[r]);
            tile[rr1 * 516 + c] = pack2(y1[r]);
        }
        __syncthreads();
        // store: per col c, rows hb..hb+15 = 64 B contiguous (uint4 per thread)
        unsigned* outF = fieldsT + (((size_t)(b * 2 + f)) << 18);
#pragma unroll
        for (int k = 0; k < 4; ++k) {
            int e = tid + (k << 9);
            int c = e >> 2, q = e & 3;
            uint4 v;
            v.x = tile[(4 * q + 0) * 516 + c];
            v.y = tile[(4 * q + 1) * 516 + c];
            v.z = tile[(4 * q + 2) * 516 + c];
            v.w = tile[(4 * q + 3) * 516 + c];
            *(uint4*)(outF + (((size_t)c) << 9) + hb + (q << 2)) = v;
        }
        __syncthreads();                 // tile dead before next pass's stage 0
    }
}

// ---------------------------------------------------------------------------
// Column pass: block = 256 thr = 4 waves; wave g owns columns 2g, 2g+1 of an
// 8-column group (ILP-2, shared twiddles). Contiguous f16 column loads
// straight into registers, wave-local FFT, fused |X|^2 + shell binning
// (overflow e>=1 skipped, f32 sqrt), LDS histogram, global-atomic flush.
// grid = NBATCH*2*64.
// ---------------------------------------------------------------------------
__global__ __launch_bounds__(256, 4)
void col_fft_bin_kernel(const unsigned* __restrict__ fieldsT,
                        float* __restrict__ bins) {
    __shared__ float2 buf[8 * 512];      // 32 KiB FFT exchange regions
    __shared__ float hist[NBINS];
    const int tid  = threadIdx.x;
    const int lane = tid & 63;
    const int g    = tid >> 6;
    const int bid  = blockIdx.x;
    const int cg   = bid & 63;
    const int fl   = bid >> 6;           // = b*2 + f
    const int f    = fl & 1;
    const int b    = fl >> 1;
    const int cA   = (cg << 3) | (g << 1);

    hist[tid] = 0.0f;
    hist[tid + 256] = 0.0f;
    __syncthreads();

    const unsigned* colA = fieldsT + ((((size_t)fl) << 9) + cA) * 512;
    const unsigned* colB = colA + 512;
    float2 a0[8], a1[8];
#pragma unroll
    for (int u = 0; u < 8; ++u) a0[u] = unpack2(colA[lane + (u << 6)]);
#pragma unroll
    for (int u = 0; u < 8; ++u) a1[u] = unpack2(colB[lane + (u << 6)]);

    float2* rb0 = buf + ((g << 1) << 9);
    float2* rb1 = rb0 + 512;
    float2 y0[8], y1[8];
    fft512_x2(rb0, rb1, lane, a0, a1, y0, y1);

    const float fcA = (float)(cA - 256)     * (1.0f / 256.0f);
    const float fcB = (float)(cA + 1 - 256) * (1.0f / 256.0f);
    const float fc2A = fcA * fcA, fc2B = fcB * fcB;
#pragma unroll
    for (int r = 0; r < 8; ++r) {
        int k = lane + (r << 6);
        float fr = (float)(k - 256) * (1.0f / 256.0f);
        float fr2 = fr * fr;
        float eA = fr2 + fc2A;           // exact in fp32
        float eB = fr2 + fc2B;
        if (eA < 1.0f) {                 // overflow shell dropped by the loss
            int bin = (int)(sqrtf(eA) * 511.0f);   // <= 510 (margin ~4e-3)
            atomicAdd(&hist[bin], y0[r].x * y0[r].x + y0[r].y * y0[r].y);
        }
        if (eB < 1.0f) {
            int bin = (int)(sqrtf(eB) * 511.0f);
            atomicAdd(&hist[bin], y1[r].x * y1[r].x + y1[r].y * y1[r].y);
        }
    }
    __syncthreads();
    float* gb = bins + ((size_t)f * NBATCH + b) * NBINS;
    atomicAdd(&gb[tid],       hist[tid]);
    atomicAdd(&gb[tid + 256], hist[tid + 256]);
}

// ---------------------------------------------------------------------------
// Loss: single block reads the 64 KiB bins array.
// loss = mean_b sum_{k<511} es[b][k] / max(ns[b][k], 1e-8)
// ---------------------------------------------------------------------------
__global__ __launch_bounds__(512)
void loss_kernel(const float* __restrict__ bins, float* __restrict__ outp) {
    __shared__ float red[512];
    const int tid = threadIdx.x;
    float acc = 0.0f;
    if (tid < 511) {
#pragma unroll 4
        for (int b = 0; b < NBATCH; ++b) {
            float ns = bins[((size_t)b) * NBINS + tid];
            float es = bins[((size_t)(NBATCH + b)) * NBINS + tid];
            acc += es / fmaxf(ns, 1e-8f);
        }
    }
    red[tid] = acc;
    __syncthreads();
    for (int s = 256; s > 0; s >>= 1) {
        if (tid < s) red[tid] += red[tid + s];
        __syncthreads();
    }
    if (tid == 0) outp[0] = red[0] * (1.0f / NBATCH);
}

// ---------------------------------------------------------------------------
extern "C" void kernel_launch(void* const* d_in, const int* in_sizes, int n_in,
                              void* d_out, int out_size, void* d_ws, size_t ws_size,
                              hipStream_t stream) {
    const float2* z = (const float2*)d_in[0];
    const float2* t = (const float2*)d_in[1];
    float* outp = (float*)d_out;

    const size_t binsBytes = (size_t)2 * NBATCH * NBINS * sizeof(float);  // 64 KiB
    // f16 intermediate: 16 batches x 2 fields x 512x512 x 4B = 32 MiB (fits ws).
    float*    bins    = (float*)d_ws;
    unsigned* fieldsT = (unsigned*)((char*)d_ws + binsBytes);

    (void)hipMemsetAsync(bins, 0, binsBytes, stream);

    row_fft_kernel<<<NBATCH * 32, 512, 0, stream>>>(z, t, fieldsT);
    col_fft_bin_kernel<<<NBATCH * 2 * 64, 256, 0, stream>>>(fieldsT, bins);
    loss_kernel<<<1, 512, 0, stream>>>(bins, outp);
}

// Round 7
// 163.800 us; speedup vs baseline: 1.0599x; 1.0599x over previous
//
#include <hip/hip_runtime.h>

#define HH 512
#define WW 512
#define NBATCH 16
#define NBINS 512   // 511 real shells + 1 overflow (never accumulated)

#define PI_F 3.14159265358979323846f

// Swizzle for the per-wave FFT exchange region (512 float2): keeps all three
// access phases at the conflict-free b64 baseline (verified R3-R5, absmax 0).
#define SW(r) ((r) ^ (((r) >> 4) & 0xF))

__device__ __forceinline__ float2 cadd(float2 a, float2 b){ return make_float2(a.x+b.x, a.y+b.y); }
__device__ __forceinline__ float2 csub(float2 a, float2 b){ return make_float2(a.x-b.x, a.y-b.y); }
__device__ __forceinline__ float2 cmul(float2 a, float2 b){
    return make_float2(a.x*b.x - a.y*b.y, a.x*b.y + a.y*b.x);
}

// f32x2 <-> packed f16x2 (v_cvt_pkrtz_f16_f32 one-instr pack)
typedef __fp16 h2v __attribute__((ext_vector_type(2)));
__device__ __forceinline__ unsigned pack2(float2 v) {
    union { h2v h; unsigned u; } c;
    c.h = __builtin_amdgcn_cvt_pkrtz(v.x, v.y);
    return c.u;
}
__device__ __forceinline__ float2 unpack2(unsigned u) {
    union { unsigned u; __fp16 h[2]; } c; c.u = u;
    return make_float2((float)c.h[0], (float)c.h[1]);
}

// 8-point DFT, y_r = sum_u a_u * w8^{ru} (forward, w8 = exp(-i pi/4)).
__device__ __forceinline__ void dft8(const float2* a, float2* y) {
    const float s2 = 0.70710678118654752440f;
    float2 t02a = cadd(a[0], a[4]), t02s = csub(a[0], a[4]);
    float2 t13a = cadd(a[2], a[6]), t13s = csub(a[2], a[6]);
    float2 E0 = cadd(t02a, t13a);
    float2 E2 = csub(t02a, t13a);
    float2 E1 = make_float2(t02s.x + t13s.y, t02s.y - t13s.x);
    float2 E3 = make_float2(t02s.x - t13s.y, t02s.y + t13s.x);
    float2 u02a = cadd(a[1], a[5]), u02s = csub(a[1], a[5]);
    float2 u13a = cadd(a[3], a[7]), u13s = csub(a[3], a[7]);
    float2 O0 = cadd(u02a, u13a);
    float2 O2 = csub(u02a, u13a);
    float2 O1 = make_float2(u02s.x + u13s.y, u02s.y - u13s.x);
    float2 O3 = make_float2(u02s.x - u13s.y, u02s.y + u13s.x);
    float2 wO1 = make_float2(s2 * (O1.x + O1.y), s2 * (O1.y - O1.x));
    float2 wO2 = make_float2(O2.y, -O2.x);
    float2 wO3 = make_float2(s2 * (O3.y - O3.x), -s2 * (O3.x + O3.y));
    y[0] = cadd(E0, O0);  y[4] = csub(E0, O0);
    y[1] = cadd(E1, wO1); y[5] = csub(E1, wO1);
    y[2] = cadd(E2, wO2); y[6] = csub(E2, wO2);
    y[3] = cadd(E3, wO3); y[7] = csub(E3, wO3);
}

__device__ __forceinline__ void twiddle8(float base, float2* w) {
    float s1, c1, s4, c4;
    __sincosf(base, &s1, &c1);
    __sincosf(4.0f * base, &s4, &c4);
    w[0] = make_float2(1.0f, 0.0f);
    w[1] = make_float2(c1, s1);
    w[2] = cmul(w[1], w[1]);
    w[3] = cmul(w[2], w[1]);
    w[4] = make_float2(c4, s4);
    w[5] = cmul(w[4], w[1]);
    w[6] = cmul(w[4], w[2]);
    w[7] = cmul(w[4], w[3]);
}

// Two interleaved radix-8 Stockham 512-pt FFTs per wave (shared twiddles).
// a0/a1 in, y0/y1 out (natural order: y[r] = X[lane + 64r]). Wave-local.
__device__ __forceinline__ void fft512_x2(float2* rb0, float2* rb1, int lane,
                                          float2* a0, float2* a1,
                                          float2* y0, float2* y1) {
    float2 w[8], y[8];
    // stage 0
    twiddle8(-PI_F * (float)lane * (1.0f / 256.0f), w);
    dft8(a0, y);
#pragma unroll
    for (int r = 0; r < 8; ++r) rb0[SW(8 * lane + r)] = cmul(y[r], w[r]);
    dft8(a1, y);
#pragma unroll
    for (int r = 0; r < 8; ++r) rb1[SW(8 * lane + r)] = cmul(y[r], w[r]);
    __builtin_amdgcn_wave_barrier();
    // stage 1
#pragma unroll
    for (int u = 0; u < 8; ++u) a0[u] = rb0[SW(lane + 64 * u)];
#pragma unroll
    for (int u = 0; u < 8; ++u) a1[u] = rb1[SW(lane + 64 * u)];
    twiddle8(-PI_F * (float)(lane >> 3) * (1.0f / 32.0f), w);
    const int qb = (lane & 7) + ((lane >> 3) << 6);
    dft8(a0, y);
#pragma unroll
    for (int r = 0; r < 8; ++r) rb0[SW(qb + 8 * r)] = cmul(y[r], w[r]);
    dft8(a1, y);
#pragma unroll
    for (int r = 0; r < 8; ++r) rb1[SW(qb + 8 * r)] = cmul(y[r], w[r]);
    __builtin_amdgcn_wave_barrier();
    // stage 2 (twiddle-free)
#pragma unroll
    for (int u = 0; u < 8; ++u) a0[u] = rb0[SW(lane + 64 * u)];
#pragma unroll
    for (int u = 0; u < 8; ++u) a1[u] = rb1[SW(lane + 64 * u)];
    dft8(a0, y0);
    dft8(a1, y1);
}

// ---------------------------------------------------------------------------
// fieldsT layout: [field][cpair][row][2] uints; word index for (col c, row r)
//   = (c>>1)*1024 + r*2 + (c&1). Column-pair data for 8 consecutive rows is
// 64 B contiguous (full-sector stores from the row pass); the col pass reads
// a column pair as uint2[row] — 512 B per wave instruction.
// ---------------------------------------------------------------------------

// ---------------------------------------------------------------------------
// Row pass: block = 256 thr = 4 waves, 8 rows of one batch. Wave g owns rows
// 2g, 2g+1 (ILP-2); t and z loaded ONCE into registers, both field FFTs run
// from regs. f16 transpose tile (8 x 516, aliased into the dead FFT exchange
// LDS) -> full 64B uint4 stores in the cpair layout. grid = NBATCH*64.
// ---------------------------------------------------------------------------
__global__ __launch_bounds__(256, 4)
void row_fft_kernel(const float2* __restrict__ z, const float2* __restrict__ t,
                    unsigned* __restrict__ fieldsT) {
    __shared__ float2 buf[8 * 512];      // 32 KiB; tile aliases low 16.5 KiB
    const int tid  = threadIdx.x;
    const int lane = tid & 63;
    const int g    = tid >> 6;
    const int bid  = blockIdx.x;
    const int hg   = bid & 63;
    const int b    = bid >> 6;
    const int hb   = hg << 3;
    const size_t off0 = (((size_t)b * HH) + hb + (g << 1)) << 9;
    const size_t off1 = off0 + 512;

    // load t and z-t once (both rows of this wave)
    float2 tv0[8], tv1[8], ev0[8], ev1[8];
#pragma unroll
    for (int u = 0; u < 8; ++u) tv0[u] = t[off0 + lane + 64 * u];
#pragma unroll
    for (int u = 0; u < 8; ++u) tv1[u] = t[off1 + lane + 64 * u];
#pragma unroll
    for (int u = 0; u < 8; ++u) {
        float2 zv = z[off0 + lane + 64 * u];
        ev0[u] = make_float2(zv.x - tv0[u].x, zv.y - tv0[u].y);
    }
#pragma unroll
    for (int u = 0; u < 8; ++u) {
        float2 zv = z[off1 + lane + 64 * u];
        ev1[u] = make_float2(zv.x - tv1[u].x, zv.y - tv1[u].y);
    }

    float2* rb0 = buf + ((g << 1) << 9);
    float2* rb1 = rb0 + 512;
    unsigned* tile = (unsigned*)buf;     // tile[rr][c]: idx = rr*516 + c
    const int rr0 = g << 1, rr1 = rr0 | 1;

#pragma unroll
    for (int f = 0; f < 2; ++f) {
        float2 a0[8], a1[8];
#pragma unroll
        for (int u = 0; u < 8; ++u) {
            a0[u] = (f == 0) ? tv0[u] : ev0[u];
            a1[u] = (f == 0) ? tv1[u] : ev1[u];
        }
        float2 y0[8], y1[8];
        fft512_x2(rb0, rb1, lane, a0, a1, y0, y1);

        __syncthreads();                 // all FFT-region reads done
#pragma unroll
        for (int r = 0; r < 8; ++r) {
            int c = lane + (r << 6);
            tile[rr0 * 516 + c] = pack2(y0[r]);
            tile[rr1 * 516 + c] = pack2(y1[r]);
        }
        __syncthreads();
        // stores: element e -> cpair cp=e>>2, row-quad q=e&3; uint4 covers
        // rows {2q,2q+1} x cols {2cp,2cp+1}; 4 consecutive lanes = 64 B.
        unsigned* outF = fieldsT + (((size_t)(b * 2 + f)) << 18);
#pragma unroll
        for (int k = 0; k < 4; ++k) {
            int e  = tid + (k << 8);
            int cp = e >> 2, q = e & 3;
            uint4 v;
            v.x = tile[(2 * q)     * 516 + 2 * cp];
            v.y = tile[(2 * q)     * 516 + 2 * cp + 1];
            v.z = tile[(2 * q + 1) * 516 + 2 * cp];
            v.w = tile[(2 * q + 1) * 516 + 2 * cp + 1];
            *(uint4*)(outF + ((size_t)cp << 10) + ((hb + 2 * q) << 1)) = v;
        }
        __syncthreads();                 // tile dead before next field's FFT
    }
}

// ---------------------------------------------------------------------------
// Column pass: block = 256 thr = 4 waves; wave g owns column pair cp0+g
// (cols 2cp, 2cp+1 — ILP-2, shared twiddles). uint2 column-pair loads
// straight into registers (512 B / wave-instr), wave-local FFT, fused
// |X|^2 + shell binning into a PER-WAVE histogram aliased into the wave's
// dead FFT exchange region (no extra LDS, no cross-wave contention), one
// __syncthreads, then fused 4-region sum + global-atomic flush.
// grid = NBATCH*2*64.
// ---------------------------------------------------------------------------
__global__ __launch_bounds__(256, 4)
void col_fft_bin_kernel(const unsigned* __restrict__ fieldsT,
                        float* __restrict__ bins) {
    __shared__ float2 buf[8 * 512];      // 32 KiB FFT exchange regions
    const int tid  = threadIdx.x;
    const int lane = tid & 63;
    const int g    = tid >> 6;
    const int bid  = blockIdx.x;
    const int cgrp = bid & 63;
    const int fl   = bid >> 6;           // = b*2 + f
    const int f    = fl & 1;
    const int b    = fl >> 1;
    const int cp   = (cgrp << 2) | g;
    const int cA   = cp << 1;

    const uint2* colP = (const uint2*)(fieldsT + (((size_t)fl) << 18) + ((size_t)cp << 10));
    float2 a0[8], a1[8];
#pragma unroll
    for (int u = 0; u < 8; ++u) {
        uint2 v = colP[lane + (u << 6)];
        a0[u] = unpack2(v.x);
        a1[u] = unpack2(v.y);
    }

    float2* rb0 = buf + ((g << 1) << 9);
    float2* rb1 = rb0 + 512;
    float2 y0[8], y1[8];
    fft512_x2(rb0, rb1, lane, a0, a1, y0, y1);
    __builtin_amdgcn_wave_barrier();

    // per-wave histogram aliased into this wave's dead rb0 region (4 KiB)
    float* Hw = (float*)rb0;
#pragma unroll
    for (int i = 0; i < 8; ++i) Hw[lane + (i << 6)] = 0.0f;
    __builtin_amdgcn_wave_barrier();

    const float fcA = (float)(cA - 256)     * (1.0f / 256.0f);
    const float fcB = (float)(cA + 1 - 256) * (1.0f / 256.0f);
    const float fc2A = fcA * fcA, fc2B = fcB * fcB;
#pragma unroll
    for (int r = 0; r < 8; ++r) {
        int k = lane + (r << 6);
        float fr = (float)(k - 256) * (1.0f / 256.0f);
        float fr2 = fr * fr;
        float eA = fr2 + fc2A;           // exact in fp32
        float eB = fr2 + fc2B;
        if (eA < 1.0f) {                 // overflow shell dropped by the loss
            int bin = (int)(sqrtf(eA) * 511.0f);   // <= 510 (margin ~4e-3)
            atomicAdd(&Hw[bin], y0[r].x * y0[r].x + y0[r].y * y0[r].y);
        }
        if (eB < 1.0f) {
            int bin = (int)(sqrtf(eB) * 511.0f);
            atomicAdd(&Hw[bin], y1[r].x * y1[r].x + y1[r].y * y1[r].y);
        }
    }
    __syncthreads();

    // flush: sum the 4 per-wave hists (regions 0,2,4,6), one global atomic/bin
    const float* H = (const float*)buf;
    float* gb = bins + ((size_t)f * NBATCH + b) * NBINS;
#pragma unroll
    for (int j = 0; j < 2; ++j) {
        int bin = tid + (j << 8);
        float s = H[bin] + H[bin + 2048] + H[bin + 4096] + H[bin + 6144];
        atomicAdd(&gb[bin], s);
    }
}

// ---------------------------------------------------------------------------
// Loss: single block reads the 64 KiB bins array.
// loss = mean_b sum_{k<511} es[b][k] / max(ns[b][k], 1e-8)
// ---------------------------------------------------------------------------
__global__ __launch_bounds__(512)
void loss_kernel(const float* __restrict__ bins, float* __restrict__ outp) {
    __shared__ float red[512];
    const int tid = threadIdx.x;
    float acc = 0.0f;
    if (tid < 511) {
#pragma unroll 4
        for (int b = 0; b < NBATCH; ++b) {
            float ns = bins[((size_t)b) * NBINS + tid];
            float es = bins[((size_t)(NBATCH + b)) * NBINS + tid];
            acc += es / fmaxf(ns, 1e-8f);
        }
    }
    red[tid] = acc;
    __syncthreads();
    for (int s = 256; s > 0; s >>= 1) {
        if (tid < s) red[tid] += red[tid + s];
        __syncthreads();
    }
    if (tid == 0) outp[0] = red[0] * (1.0f / NBATCH);
}

// ---------------------------------------------------------------------------
extern "C" void kernel_launch(void* const* d_in, const int* in_sizes, int n_in,
                              void* d_out, int out_size, void* d_ws, size_t ws_size,
                              hipStream_t stream) {
    const float2* z = (const float2*)d_in[0];
    const float2* t = (const float2*)d_in[1];
    float* outp = (float*)d_out;

    const size_t binsBytes = (size_t)2 * NBATCH * NBINS * sizeof(float);  // 64 KiB
    // f16 intermediate: 16 batches x 2 fields x 512x512 x 4B = 32 MiB.
    float*    bins    = (float*)d_ws;
    unsigned* fieldsT = (unsigned*)((char*)d_ws + binsBytes);

    (void)hipMemsetAsync(bins, 0, binsBytes, stream);

    row_fft_kernel<<<NBATCH * 64, 256, 0, stream>>>(z, t, fieldsT);
    col_fft_bin_kernel<<<NBATCH * 2 * 64, 256, 0, stream>>>(fieldsT, bins);
    loss_kernel<<<1, 512, 0, stream>>>(bins, outp);
}

// Round 8
// 161.040 us; speedup vs baseline: 1.0780x; 1.0171x over previous
//
#include <hip/hip_runtime.h>

#define HH 512
#define WW 512
#define NBATCH 16
#define NBINS 512   // 511 real shells + 1 overflow bin (never read by the loss)
#define NCG 64      // column groups (8 columns each)

#define PI_F 3.14159265358979323846f

// Swizzle for the per-wave FFT exchange region (512 float2): keeps all three
// access phases at the conflict-free b64 baseline (verified R3-R7, absmax 0).
#define SW(r) ((r) ^ (((r) >> 4) & 0xF))

__device__ __forceinline__ float2 cadd(float2 a, float2 b){ return make_float2(a.x+b.x, a.y+b.y); }
__device__ __forceinline__ float2 csub(float2 a, float2 b){ return make_float2(a.x-b.x, a.y-b.y); }
__device__ __forceinline__ float2 cmul(float2 a, float2 b){
    return make_float2(a.x*b.x - a.y*b.y, a.x*b.y + a.y*b.x);
}

// f32x2 <-> packed f16x2 (v_cvt_pkrtz_f16_f32 one-instr pack)
typedef __fp16 h2v __attribute__((ext_vector_type(2)));
__device__ __forceinline__ unsigned pack2(float2 v) {
    union { h2v h; unsigned u; } c;
    c.h = __builtin_amdgcn_cvt_pkrtz(v.x, v.y);
    return c.u;
}
__device__ __forceinline__ float2 unpack2(unsigned u) {
    union { unsigned u; __fp16 h[2]; } c; c.u = u;
    return make_float2((float)c.h[0], (float)c.h[1]);
}

// 8-point DFT, y_r = sum_u a_u * w8^{ru} (forward, w8 = exp(-i pi/4)).
__device__ __forceinline__ void dft8(const float2* a, float2* y) {
    const float s2 = 0.70710678118654752440f;
    float2 t02a = cadd(a[0], a[4]), t02s = csub(a[0], a[4]);
    float2 t13a = cadd(a[2], a[6]), t13s = csub(a[2], a[6]);
    float2 E0 = cadd(t02a, t13a);
    float2 E2 = csub(t02a, t13a);
    float2 E1 = make_float2(t02s.x + t13s.y, t02s.y - t13s.x);
    float2 E3 = make_float2(t02s.x - t13s.y, t02s.y + t13s.x);
    float2 u02a = cadd(a[1], a[5]), u02s = csub(a[1], a[5]);
    float2 u13a = cadd(a[3], a[7]), u13s = csub(a[3], a[7]);
    float2 O0 = cadd(u02a, u13a);
    float2 O2 = csub(u02a, u13a);
    float2 O1 = make_float2(u02s.x + u13s.y, u02s.y - u13s.x);
    float2 O3 = make_float2(u02s.x - u13s.y, u02s.y + u13s.x);
    float2 wO1 = make_float2(s2 * (O1.x + O1.y), s2 * (O1.y - O1.x));
    float2 wO2 = make_float2(O2.y, -O2.x);
    float2 wO3 = make_float2(s2 * (O3.y - O3.x), -s2 * (O3.x + O3.y));
    y[0] = cadd(E0, O0);  y[4] = csub(E0, O0);
    y[1] = cadd(E1, wO1); y[5] = csub(E1, wO1);
    y[2] = cadd(E2, wO2); y[6] = csub(E2, wO2);
    y[3] = cadd(E3, wO3); y[7] = csub(E3, wO3);
}

__device__ __forceinline__ void twiddle8(float base, float2* w) {
    float s1, c1, s4, c4;
    __sincosf(base, &s1, &c1);
    __sincosf(4.0f * base, &s4, &c4);
    w[0] = make_float2(1.0f, 0.0f);
    w[1] = make_float2(c1, s1);
    w[2] = cmul(w[1], w[1]);
    w[3] = cmul(w[2], w[1]);
    w[4] = make_float2(c4, s4);
    w[5] = cmul(w[4], w[1]);
    w[6] = cmul(w[4], w[2]);
    w[7] = cmul(w[4], w[3]);
}

// Two interleaved radix-8 Stockham 512-pt FFTs per wave (shared twiddles).
// a0/a1 in (clobbered), y0/y1 out (natural order: y[r] = X[lane+64r]).
__device__ __forceinline__ void fft512_x2(float2* rb0, float2* rb1, int lane,
                                          float2* a0, float2* a1,
                                          float2* y0, float2* y1) {
    float2 w[8], y[8];
    // stage 0
    twiddle8(-PI_F * (float)lane * (1.0f / 256.0f), w);
    dft8(a0, y);
#pragma unroll
    for (int r = 0; r < 8; ++r) rb0[SW(8 * lane + r)] = cmul(y[r], w[r]);
    dft8(a1, y);
#pragma unroll
    for (int r = 0; r < 8; ++r) rb1[SW(8 * lane + r)] = cmul(y[r], w[r]);
    __builtin_amdgcn_wave_barrier();
    // stage 1
#pragma unroll
    for (int u = 0; u < 8; ++u) a0[u] = rb0[SW(lane + 64 * u)];
#pragma unroll
    for (int u = 0; u < 8; ++u) a1[u] = rb1[SW(lane + 64 * u)];
    twiddle8(-PI_F * (float)(lane >> 3) * (1.0f / 32.0f), w);
    const int qb = (lane & 7) + ((lane >> 3) << 6);
    dft8(a0, y);
#pragma unroll
    for (int r = 0; r < 8; ++r) rb0[SW(qb + 8 * r)] = cmul(y[r], w[r]);
    dft8(a1, y);
#pragma unroll
    for (int r = 0; r < 8; ++r) rb1[SW(qb + 8 * r)] = cmul(y[r], w[r]);
    __builtin_amdgcn_wave_barrier();
    // stage 2 (twiddle-free)
#pragma unroll
    for (int u = 0; u < 8; ++u) a0[u] = rb0[SW(lane + 64 * u)];
#pragma unroll
    for (int u = 0; u < 8; ++u) a1[u] = rb1[SW(lane + 64 * u)];
    dft8(a0, y0);
    dft8(a1, y1);
}

// ---------------------------------------------------------------------------
// fieldsT layout: [field][cpair][row][2] uints; word index for (col c, row r)
//   = (c>>1)*1024 + r*2 + (c&1). Row pass stores full 64B sectors; col pass
// reads a column pair as uint2[row] (512 B per wave instruction).
// ---------------------------------------------------------------------------

// ---------------------------------------------------------------------------
// Row pass: block = 256 thr = 4 waves, 8 rows of one batch. Wave g owns rows
// 2g, 2g+1 (ILP-2). Per-field loads (no cross-field register hold -> no
// spill; the f=1 re-read of t is an L2 hit). f16 transpose tile (aliased
// into the dead FFT exchange LDS) -> full 64B uint4 stores. grid = NBATCH*64.
// ---------------------------------------------------------------------------
__global__ __launch_bounds__(256, 4)
void row_fft_kernel(const float2* __restrict__ z, const float2* __restrict__ t,
                    unsigned* __restrict__ fieldsT) {
    __shared__ float2 buf[8 * 512];      // 32 KiB; tile aliases low 16.5 KiB
    const int tid  = threadIdx.x;
    const int lane = tid & 63;
    const int g    = tid >> 6;
    const int bid  = blockIdx.x;
    const int hg   = bid & 63;
    const int b    = bid >> 6;
    const int hb   = hg << 3;
    const size_t off0 = (((size_t)b * HH) + hb + (g << 1)) << 9;
    const size_t off1 = off0 + 512;

    float2* rb0 = buf + ((g << 1) << 9);
    float2* rb1 = rb0 + 512;
    unsigned* tile = (unsigned*)buf;     // tile[rr][c]: idx = rr*516 + c
    const int rr0 = g << 1, rr1 = rr0 | 1;

#pragma unroll
    for (int f = 0; f < 2; ++f) {
        float2 a0[8], a1[8];
        if (f == 0) {
#pragma unroll
            for (int u = 0; u < 8; ++u) a0[u] = t[off0 + lane + 64 * u];
#pragma unroll
            for (int u = 0; u < 8; ++u) a1[u] = t[off1 + lane + 64 * u];
        } else {
#pragma unroll
            for (int u = 0; u < 8; ++u) {
                float2 zv = z[off0 + lane + 64 * u];
                float2 tv = t[off0 + lane + 64 * u];
                a0[u] = make_float2(zv.x - tv.x, zv.y - tv.y);
            }
#pragma unroll
            for (int u = 0; u < 8; ++u) {
                float2 zv = z[off1 + lane + 64 * u];
                float2 tv = t[off1 + lane + 64 * u];
                a1[u] = make_float2(zv.x - tv.x, zv.y - tv.y);
            }
        }
        float2 y0[8], y1[8];
        fft512_x2(rb0, rb1, lane, a0, a1, y0, y1);

        __syncthreads();                 // all FFT-region reads done
#pragma unroll
        for (int r = 0; r < 8; ++r) {
            int c = lane + (r << 6);
            tile[rr0 * 516 + c] = pack2(y0[r]);
            tile[rr1 * 516 + c] = pack2(y1[r]);
        }
        __syncthreads();
        // stores: element e -> cpair cp=e>>2, row-quad q=e&3; uint4 covers
        // rows {2q,2q+1} x cols {2cp,2cp+1}; 4 consecutive lanes = 64 B.
        unsigned* outF = fieldsT + (((size_t)(b * 2 + f)) << 18);
#pragma unroll
        for (int k = 0; k < 4; ++k) {
            int e  = tid + (k << 8);
            int cp = e >> 2, q = e & 3;
            uint4 v;
            v.x = tile[(2 * q)     * 516 + 2 * cp];
            v.y = tile[(2 * q)     * 516 + 2 * cp + 1];
            v.z = tile[(2 * q + 1) * 516 + 2 * cp];
            v.w = tile[(2 * q + 1) * 516 + 2 * cp + 1];
            *(uint4*)(outF + ((size_t)cp << 10) + ((hb + 2 * q) << 1)) = v;
        }
        __syncthreads();                 // tile dead before next field's FFT
    }
}

// ---------------------------------------------------------------------------
// Segmented wave reduction for one 64-lane chunk of shell binning.
// bin(k) is monotone in lane within a chunk -> equal bins are contiguous;
// suffix-sum segments via shfl_down, leaders do non-atomic distinct-address
// LDS RMW. Overflow pixels (e >= 1) land in bin 511 which is never read.
// ---------------------------------------------------------------------------
__device__ __forceinline__ void bin_chunk(float* Hw, int lane, int k,
                                          float fc2, float mag) {
    float fr = (float)(k - 256) * (1.0f / 256.0f);
    float e  = fr * fr + fc2;            // exact in fp32
    int bin = min((int)(sqrtf(e) * 511.0f), 511);
    float v = mag;
#pragma unroll
    for (int d = 1; d < 64; d <<= 1) {
        float ov = __shfl_down(v, d, 64);
        int   ob = __shfl_down(bin, d, 64);
        if (((lane + d) < 64) && (ob == bin)) v += ov;
    }
    int pb = __shfl_up(bin, 1, 64);
    if (lane == 0 || pb != bin) Hw[bin] += v;   // distinct addrs in wave
}

// ---------------------------------------------------------------------------
// Column pass: block = 256 thr = 4 waves; wave g owns column pair
// cgrp*4+g (cols 2cp, 2cp+1 — ILP-2, shared twiddles). uint2 column-pair
// loads straight into registers, wave-local FFT, fused |X|^2 + seg-reduce
// shell binning into a per-wave hist aliased in the dead FFT region. NO
// atomics anywhere: one __syncthreads, then non-atomic partial flush.
// grid = NBATCH*2*64.
// ---------------------------------------------------------------------------
__global__ __launch_bounds__(256, 4)
void col_fft_bin_kernel(const unsigned* __restrict__ fieldsT,
                        float* __restrict__ partials) {
    __shared__ float2 buf[8 * 512];      // 32 KiB FFT exchange regions
    const int tid  = threadIdx.x;
    const int lane = tid & 63;
    const int g    = tid >> 6;
    const int bid  = blockIdx.x;
    const int cgrp = bid & 63;
    const int fl   = bid >> 6;           // = b*2 + f
    const int cp   = (cgrp << 2) | g;
    const int cA   = cp << 1;

    const uint2* colP = (const uint2*)(fieldsT + (((size_t)fl) << 18) + ((size_t)cp << 10));
    float2 a0[8], a1[8];
#pragma unroll
    for (int u = 0; u < 8; ++u) {
        uint2 v = colP[lane + (u << 6)];
        a0[u] = unpack2(v.x);
        a1[u] = unpack2(v.y);
    }

    float2* rb0 = buf + ((g << 1) << 9);
    float2* rb1 = rb0 + 512;
    float2 y0[8], y1[8];
    fft512_x2(rb0, rb1, lane, a0, a1, y0, y1);
    __builtin_amdgcn_wave_barrier();

    // per-wave histogram aliased into this wave's dead rb0 region (2 KiB)
    float* Hw = (float*)rb0;
#pragma unroll
    for (int i = 0; i < 8; ++i) Hw[lane + (i << 6)] = 0.0f;
    __builtin_amdgcn_wave_barrier();

    const float fcA = (float)(cA - 256)     * (1.0f / 256.0f);
    const float fcB = (float)(cA + 1 - 256) * (1.0f / 256.0f);
    const float fc2A = fcA * fcA, fc2B = fcB * fcB;
#pragma unroll
    for (int r = 0; r < 8; ++r) {
        int k = lane + (r << 6);
        bin_chunk(Hw, lane, k, fc2A, y0[r].x * y0[r].x + y0[r].y * y0[r].y);
        bin_chunk(Hw, lane, k, fc2B, y1[r].x * y1[r].x + y1[r].y * y1[r].y);
    }
    __syncthreads();

    // non-atomic flush: sum the 4 per-wave hists (float offsets 0/2048/4096/
    // 6144), coalesced store into this block's private partial slice.
    const float* H = (const float*)buf;
    float* pb = partials + (((size_t)fl * NCG) + cgrp) * NBINS;
#pragma unroll
    for (int j = 0; j < 2; ++j) {
        int bin = tid + (j << 8);
        pb[bin] = H[bin] + H[bin + 2048] + H[bin + 4096] + H[bin + 6144];
    }
}

// ---------------------------------------------------------------------------
// Loss: one block per batch; coalesced reduce of the 64 column-group
// partials for both fields, ratio per shell, block-reduce, atomic batch mean.
// ---------------------------------------------------------------------------
__global__ __launch_bounds__(512)
void loss_kernel(const float* __restrict__ partials, float* __restrict__ outp) {
    __shared__ float red[512];
    const int b = blockIdx.x;
    const int tid = threadIdx.x;
    float ns = 0.0f, es = 0.0f;
    const float* pn = partials + ((size_t)(b * 2 + 0) * NCG) * NBINS + tid;
    const float* pe = partials + ((size_t)(b * 2 + 1) * NCG) * NBINS + tid;
#pragma unroll 4
    for (int cg = 0; cg < NCG; ++cg) {
        ns += pn[cg * NBINS];            // coalesced 2 KiB per iteration
        es += pe[cg * NBINS];
    }
    red[tid] = (tid < 511) ? es / fmaxf(ns, 1e-8f) : 0.0f;
    __syncthreads();
    for (int s = 256; s > 0; s >>= 1) {
        if (tid < s) red[tid] += red[tid + s];
        __syncthreads();
    }
    if (tid == 0) atomicAdd(outp, red[0] * (1.0f / NBATCH));
}

// ---------------------------------------------------------------------------
extern "C" void kernel_launch(void* const* d_in, const int* in_sizes, int n_in,
                              void* d_out, int out_size, void* d_ws, size_t ws_size,
                              hipStream_t stream) {
    const float2* z = (const float2*)d_in[0];
    const float2* t = (const float2*)d_in[1];
    float* outp = (float*)d_out;

    // ws: partials (2*16*64*512*4 = 4 MiB) + f16 fieldsT (32 MiB) = 36.06 MiB
    // (identical budget to R3's proven-fitting layout).
    const size_t partBytes = (size_t)2 * NBATCH * NCG * NBINS * sizeof(float);
    float*    partials = (float*)d_ws;
    unsigned* fieldsT  = (unsigned*)((char*)d_ws + partBytes);

    (void)hipMemsetAsync(outp, 0, sizeof(float), stream);

    row_fft_kernel<<<NBATCH * 64, 256, 0, stream>>>(z, t, fieldsT);
    col_fft_bin_kernel<<<NBATCH * 2 * 64, 256, 0, stream>>>(fieldsT, partials);
    loss_kernel<<<NBATCH, 512, 0, stream>>>(partials, outp);
}